// Round 2
// 1444.854 us; speedup vs baseline: 1.1894x; 1.1894x over previous
//
#include <hip/hip_runtime.h>
#include <hip/hip_bf16.h>

typedef __attribute__((ext_vector_type(8))) short short8;
typedef __attribute__((ext_vector_type(4))) float floatx4;
typedef __attribute__((ext_vector_type(4))) int intx4;

__device__ __forceinline__ float bits2f(unsigned short u) {
    union { unsigned int i; float f; } v; v.i = ((unsigned int)u) << 16; return v.f;
}
__device__ __forceinline__ unsigned short f2bb(float x) {  // RNE f32->bf16 bits
    union { float f; unsigned int i; } v; v.f = x;
    unsigned int r = v.i + 0x7FFFu + ((v.i >> 16) & 1u);
    return (unsigned short)(r >> 16);
}
// dtype-agnostic scalar load (fp32 flag is wave-uniform)
__device__ __forceinline__ float ldf(const void* base, long i, int fp32) {
    return fp32 ? ((const float*)base)[i] : bits2f(((const unsigned short*)base)[i]);
}
// dtype-agnostic 8-element row fragment load -> bf16 bits (vectorized both paths)
__device__ __forceinline__ short8 loadRow8(const void* base, long off, int fp32) {
    short8 r;
    if (!fp32) {
        r = *(const short8*)((const unsigned short*)base + off);
    } else {
        const float* f = (const float*)base + off;
        floatx4 f0 = *(const floatx4*)f;
        floatx4 f1 = *(const floatx4*)(f + 4);
        #pragma unroll
        for (int j = 0; j < 4; ++j) {
            r[j]     = (short)f2bb(f0[j]);
            r[j + 4] = (short)f2bb(f1[j]);
        }
    }
    return r;
}
__device__ __forceinline__ float lclamp(float z) {  // NaN-laundering clamp
    return fminf(fmaxf(z, -1e4f), 1e4f);
}

// ---------------------------------------------------------------------------
// Probe: decide if float tensors are fp32 or bf16.
// ---------------------------------------------------------------------------
__global__ void k_probe(const unsigned short* __restrict__ Wb, int* __restrict__ flag) {
    int t = threadIdx.x;                 // 64 threads
    unsigned short u = Wb[t * 2];        // even-indexed u16
    unsigned e = (u >> 7) & 0xFF;        // bf16 exponent field
    int in = (e >= 0x60 && e <= 0x8F) ? 1 : 0;
    unsigned long long m = __ballot(in);
    if (t == 0) flag[0] = (__popcll(m) < 32) ? 1 : 0;   // 1 => fp32
}

// ---------------------------------------------------------------------------
// K1: per-atom projection into GATHER-FRIENDLY layout:
//   P_u16[a*256 + half*128 + n0*8 + tt]  holds column (tt*16+n0) of half
//   half 0: atom[a]@W[0:64,:]+b   half 1: atom[a]@W[64:128,:]
// Each lane packs 8 bf16 (tt=0..7) for fixed (a, n0) -> one 16B store.
// ---------------------------------------------------------------------------
__global__ __launch_bounds__(256) void k_atom_proj(
    const void* __restrict__ atom,
    const void* __restrict__ Wv,         // [192][128]
    const void* __restrict__ bv,         // [128]
    __hip_bfloat16* __restrict__ P, int N, const int* __restrict__ flagp)
{
    const int fp32 = *flagp;
    const int t = threadIdx.x;
    const int wave = t >> 6, lane = t & 63;
    const int half = wave & 1;
    const int pairInBlk = wave >> 1;
    const int n0 = lane & 15, kq = lane >> 4;
    unsigned short* Pu = (unsigned short*)P;

    short8 bf[8][2];
    #pragma unroll
    for (int tt = 0; tt < 8; ++tt)
        #pragma unroll
        for (int h = 0; h < 2; ++h)
            #pragma unroll
            for (int jj = 0; jj < 8; ++jj) {
                int k = half*64 + h*32 + kq*8 + jj;
                bf[tt][h][jj] = (short)f2bb(ldf(Wv, (long)k*128 + tt*16 + n0, fp32));
            }
    float bias[8];
    #pragma unroll
    for (int tt = 0; tt < 8; ++tt)
        bias[tt] = half ? 0.f : ldf(bv, tt*16 + n0, fp32);

    const long nGroups = ((long)N + 15) / 16;
    for (long g = (long)blockIdx.x*2 + pairInBlk; g < nGroups; g += (long)gridDim.x*2) {
        long a0 = g * 16;
        long am = a0 + n0;
        short8 a_lo = {}, a_hi = {};
        if (am < N) {
            a_lo = loadRow8(atom, am*64 + kq*8, fp32);
            a_hi = loadRow8(atom, am*64 + 32 + kq*8, fp32);
        }
        floatx4 acc[8];
        #pragma unroll
        for (int tt = 0; tt < 8; ++tt) {
            floatx4 c = {0.f, 0.f, 0.f, 0.f};
            c = __builtin_amdgcn_mfma_f32_16x16x32_bf16(a_lo, bf[tt][0], c, 0, 0, 0);
            c = __builtin_amdgcn_mfma_f32_16x16x32_bf16(a_hi, bf[tt][1], c, 0, 0, 0);
            acc[tt] = c;
        }
        #pragma unroll
        for (int r = 0; r < 4; ++r) {
            long a = a0 + kq*4 + r;
            if (a < N) {
                short8 v;
                #pragma unroll
                for (int tt = 0; tt < 8; ++tt)
                    v[tt] = (short)f2bb(lclamp(acc[tt][r] + bias[tt]));
                *(short8*)(Pu + a*256 + half*128 + n0*8) = v;   // 16B coalesced
            }
        }
    }
}

// ---------------------------------------------------------------------------
// K2/K4: edge pass. z_e[n] = (nbr_e @ W3)[n] + P1[src_e][n] + P2[dst_e][n]
// W3 fragments live in LDS (16KB, staged once/block) -> frees 64 VGPRs.
// P gathers: one short8 (16B) vector load per (edge, half) per lane.
// ---------------------------------------------------------------------------
template<int PHASE>
__global__ __launch_bounds__(256, 4) void k_edge(
    const void* __restrict__ nbr,
    const int* __restrict__ esrc,
    const int* __restrict__ edst,
    const void* __restrict__ Wv,
    const unsigned short* __restrict__ Pb,   // bf16 bits, [N][2][16][8]
    const float* __restrict__ coef,
    float* __restrict__ outAcc,
    long E, const int* __restrict__ flagp)
{
    __shared__ unsigned short s_w[8192];     // 16 frags x 64 lanes x 8 u16 = 16KB
    __shared__ float s_sum[128], s_ss[128];
    const int fp32 = *flagp;
    const int t = threadIdx.x;
    const int wave = t >> 6, lane = t & 63;
    const int n0 = lane & 15, kq = lane >> 4;

    // stage W3 fragments: frag f = tt*2+h; s_w[f*512 + l*8 + jj]
    for (int idx = t; idx < 8192; idx += 256) {
        int f  = idx >> 9;
        int l  = (idx >> 3) & 63;
        int jj = idx & 7;
        int tt = f >> 1, h = f & 1;
        int k = 128 + h*32 + (l >> 4)*8 + jj;
        s_w[idx] = f2bb(ldf(Wv, (long)k*128 + tt*16 + (l & 15), fp32));
    }
    if (PHASE == 0 && t < 128) { s_sum[t] = 0.f; s_ss[t] = 0.f; }
    __syncthreads();

    float sc[8], sh[8];
    if (PHASE == 1) {
        #pragma unroll
        for (int tt = 0; tt < 8; ++tt) {
            sc[tt] = coef[tt*16 + n0];
            sh[tt] = coef[128 + tt*16 + n0];
        }
    }
    float lsum[8], lss[8];
    if (PHASE == 0) {
        #pragma unroll
        for (int tt = 0; tt < 8; ++tt) { lsum[tt] = 0.f; lss[tt] = 0.f; }
    }

    const unsigned short* swl = &s_w[lane * 8];   // per-lane fragment base

    const long nGroups = (E + 15) / 16;
    for (long g = (long)blockIdx.x*4 + wave; g < nGroups; g += (long)gridDim.x*4) {
        const long e0 = g * 16;
        const bool full = (e0 + 16 <= E);

        // endpoint indices: 4 consecutive edges per quarter-wave, one 16B load
        intx4 sv, dv;
        if (full) {
            sv = *(const intx4*)(esrc + e0 + kq*4);
            dv = *(const intx4*)(edst + e0 + kq*4);
        } else {
            #pragma unroll
            for (int r = 0; r < 4; ++r) {
                long er = e0 + kq*4 + r;
                sv[r] = (er < E) ? esrc[er] : 0;
                dv[r] = (er < E) ? edst[er] : 0;
            }
        }
        // P gathers: 8 independent 16B loads, issued before all consumers.
        // Quarter-wave (16 lanes, n0=0..15) covers a contiguous 256B row-half.
        short8 vs[4], vd[4];
        #pragma unroll
        for (int r = 0; r < 4; ++r) {
            vs[r] = *(const short8*)(Pb + (long)sv[r]*256 + n0*8);
            vd[r] = *(const short8*)(Pb + (long)dv[r]*256 + 128 + n0*8);
        }
        // A rows (nbr stream)
        long ea = e0 + n0;
        short8 a_lo = {}, a_hi = {};
        if (ea < E) {
            a_lo = loadRow8(nbr, ea*64 + kq*8, fp32);
            a_hi = loadRow8(nbr, ea*64 + 32 + kq*8, fp32);
        }
        // u = nbr @ W3 (B fragments from LDS; overlaps with P gathers in flight)
        floatx4 acc[8];
        #pragma unroll
        for (int tt = 0; tt < 8; ++tt) {
            short8 b0 = *(const short8*)(swl + (tt*2 + 0)*512);
            short8 b1 = *(const short8*)(swl + (tt*2 + 1)*512);
            floatx4 c = {0.f, 0.f, 0.f, 0.f};
            c = __builtin_amdgcn_mfma_f32_16x16x32_bf16(a_lo, b0, c, 0, 0, 0);
            c = __builtin_amdgcn_mfma_f32_16x16x32_bf16(a_hi, b1, c, 0, 0, 0);
            acc[tt] = c;
        }

        if (PHASE == 0) {
            if (full) {
                #pragma unroll
                for (int tt = 0; tt < 8; ++tt)
                    #pragma unroll
                    for (int r = 0; r < 4; ++r) {
                        float z = lclamp(acc[tt][r]
                                + bits2f((unsigned short)vs[r][tt])
                                + bits2f((unsigned short)vd[r][tt]));
                        lsum[tt] += z; lss[tt] += z*z;
                    }
            } else {
                #pragma unroll
                for (int tt = 0; tt < 8; ++tt)
                    #pragma unroll
                    for (int r = 0; r < 4; ++r) {
                        long er = e0 + kq*4 + r;
                        if (er < E) {
                            float z = lclamp(acc[tt][r]
                                    + bits2f((unsigned short)vs[r][tt])
                                    + bits2f((unsigned short)vd[r][tt]));
                            lsum[tt] += z; lss[tt] += z*z;
                        }
                    }
            }
        } else {
            #pragma unroll
            for (int tt = 0; tt < 4; ++tt)
                #pragma unroll
                for (int r = 0; r < 4; ++r) {
                    long er = e0 + kq*4 + r;
                    if (full || er < E) {
                        float zf = lclamp(acc[tt][r]
                                 + bits2f((unsigned short)vs[r][tt])
                                 + bits2f((unsigned short)vd[r][tt])) * sc[tt] + sh[tt];
                        float zc = lclamp(acc[tt+4][r]
                                 + bits2f((unsigned short)vs[r][tt+4])
                                 + bits2f((unsigned short)vd[r][tt+4])) * sc[tt+4] + sh[tt+4];
                        float sig = 1.f / (1.f + __expf(-zf));
                        float sp  = fmaxf(zc, 0.f) + log1pf(__expf(-fabsf(zc)));
                        atomicAdd(outAcc + (long)dv[r]*64 + tt*16 + n0, sig * sp);
                    }
                }
        }
    }
    if (PHASE == 0) {
        __syncthreads();
        #pragma unroll
        for (int tt = 0; tt < 8; ++tt) {
            atomicAdd(&s_sum[tt*16 + n0], lsum[tt]);
            atomicAdd(&s_ss[tt*16 + n0], lss[tt]);
        }
        __syncthreads();
        if (t < 128) {
            atomicAdd(&outAcc[t], s_sum[t]);
            atomicAdd(&outAcc[128 + t], s_ss[t]);
        }
    }
}

// ---------------------------------------------------------------------------
__global__ void k_fin1(const float* __restrict__ stats,
                       const void* __restrict__ gamma,
                       const void* __restrict__ beta,
                       float* __restrict__ coef, float invE,
                       const int* __restrict__ flagp)
{
    const int fp32 = *flagp;
    int t = threadIdx.x;  // 128
    float mean = stats[t] * invE;
    float var  = fmaxf(stats[128 + t] * invE - mean * mean, 0.f);
    float sc = ldf(gamma, t, fp32) * rsqrtf(var + 1e-5f);
    coef[t] = sc;
    coef[128 + t] = ldf(beta, t, fp32) - mean * sc;
}

__global__ void k_au_stats(const float* __restrict__ au, float* __restrict__ stats, int N)
{
    __shared__ float s_red[256];
    int t = threadIdx.x;
    int j = t & 63, r = t >> 6;
    float lsum = 0.f, lss = 0.f;
    for (int base = blockIdx.x * 4; base < N; base += gridDim.x * 4) {
        int a = base + r;
        if (a < N) { float v = au[(long)a*64 + j]; lsum += v; lss += v*v; }
    }
    s_red[t] = lsum; __syncthreads();
    if (t < 64) atomicAdd(&stats[j], s_red[j] + s_red[j+64] + s_red[j+128] + s_red[j+192]);
    __syncthreads();
    s_red[t] = lss; __syncthreads();
    if (t < 64) atomicAdd(&stats[64+j], s_red[j] + s_red[j+64] + s_red[j+128] + s_red[j+192]);
}

__global__ void k_fin2(const float* __restrict__ stats,
                       const void* __restrict__ gamma,
                       const void* __restrict__ beta,
                       float* __restrict__ coef, float invN,
                       const int* __restrict__ flagp)
{
    const int fp32 = *flagp;
    int t = threadIdx.x;  // 64
    float mean = stats[t] * invN;
    float var  = fmaxf(stats[64 + t] * invN - mean * mean, 0.f);
    float sc = ldf(gamma, t, fp32) * rsqrtf(var + 1e-5f);
    coef[t] = sc;
    coef[64 + t] = ldf(beta, t, fp32) - mean * sc;
}

__global__ void k_out(const void* __restrict__ atom,
                      const float* __restrict__ au,
                      const float* __restrict__ coef2,
                      void* __restrict__ out, long total,
                      const int* __restrict__ flagp)
{
    const int fp32 = *flagp;
    long i = (long)blockIdx.x * blockDim.x + threadIdx.x;
    if (i >= total) return;
    int j = (int)(i & 63);
    float x = lclamp(ldf(atom, i, fp32) + au[i] * coef2[j] + coef2[64 + j]);
    float sp = fmaxf(x, 0.f) + log1pf(__expf(-fabsf(x)));
    if (fp32) ((float*)out)[i] = sp;
    else      ((__hip_bfloat16*)out)[i] = __float2bfloat16(sp);
}

// ---------------------------------------------------------------------------
extern "C" void kernel_launch(void* const* d_in, const int* in_sizes, int n_in,
                              void* d_out, int out_size, void* d_ws, size_t ws_size,
                              hipStream_t stream)
{
    const void* atom = d_in[0];
    const void* nbr  = d_in[1];
    const int* esrc = (const int*)d_in[2];
    const int* edst = (const int*)d_in[3];
    const void* Wv  = d_in[4];
    const void* bv  = d_in[5];
    const void* g1  = d_in[6];
    const void* be1 = d_in[7];
    const void* g2  = d_in[8];
    const void* be2 = d_in[9];

    const int  N = in_sizes[0] / 64;
    const long E = (long)in_sizes[1] / 64;

    char* w = (char*)d_ws;
    __hip_bfloat16* P = (__hip_bfloat16*)w;  w += (size_t)N * 256 * sizeof(__hip_bfloat16);
    float* au     = (float*)w;               w += (size_t)N * 64 * sizeof(float);
    float* stats1 = (float*)w;               w += 256 * sizeof(float);
    float* stats2 = (float*)w;               w += 128 * sizeof(float);
    float* coef1  = (float*)w;               w += 256 * sizeof(float);
    float* coef2  = (float*)w;               w += 128 * sizeof(float);
    int* flagp    = (int*)w;

    hipMemsetAsync(au, 0, (size_t)N * 64 * sizeof(float), stream);
    hipMemsetAsync(stats1, 0, 384 * sizeof(float), stream);

    k_probe<<<1, 64, 0, stream>>>((const unsigned short*)Wv, flagp);
    k_atom_proj<<<1024, 256, 0, stream>>>(atom, Wv, bv, P, N, flagp);
    k_edge<0><<<2048, 256, 0, stream>>>(nbr, esrc, edst, Wv,
                                        (const unsigned short*)P, nullptr, stats1, E, flagp);
    k_fin1<<<1, 128, 0, stream>>>(stats1, g1, be1, coef1, 1.0f / (float)E, flagp);
    k_edge<1><<<2048, 256, 0, stream>>>(nbr, esrc, edst, Wv,
                                        (const unsigned short*)P, coef1, au, E, flagp);
    k_au_stats<<<1024, 256, 0, stream>>>(au, stats2, N);
    k_fin2<<<1, 64, 0, stream>>>(stats2, g2, be2, coef2, 1.0f / (float)N, flagp);
    long total = (long)N * 64;
    k_out<<<(int)((total + 255) / 256), 256, 0, stream>>>(atom, au, coef2,
                                                          d_out, total, flagp);
}

// Round 3
// 1373.254 us; speedup vs baseline: 1.2514x; 1.0521x over previous
//
#include <hip/hip_runtime.h>
#include <hip/hip_bf16.h>

typedef __attribute__((ext_vector_type(8))) short short8;
typedef __attribute__((ext_vector_type(4))) float floatx4;
typedef __attribute__((ext_vector_type(4))) int intx4;
typedef __attribute__((ext_vector_type(4))) unsigned int uintx4;
typedef __attribute__((ext_vector_type(2))) float f32x2;

__device__ __forceinline__ float bits2f(unsigned short u) {
    union { unsigned int i; float f; } v; v.i = ((unsigned int)u) << 16; return v.f;
}
__device__ __forceinline__ unsigned short f2bb(float x) {  // RNE f32->bf16 bits
    union { float f; unsigned int i; } v; v.f = x;
    unsigned int r = v.i + 0x7FFFu + ((v.i >> 16) & 1u);
    return (unsigned short)(r >> 16);
}
// unpack 2 bf16 (packed in u32) -> 2 f32 in 2 VALU ops
__device__ __forceinline__ f32x2 unpk(unsigned int w) {
    union { unsigned int i; float f; } lo, hi;
    lo.i = w << 16;
    hi.i = w & 0xFFFF0000u;
    f32x2 r; r[0] = lo.f; r[1] = hi.f; return r;
}
// pack 2 f32 -> u32 of 2 bf16 (RNE); compiler maps to v_cvt_pk_bf16_f32
__device__ __forceinline__ unsigned int pk2bb(float a, float b) {
    union { __hip_bfloat162 h; unsigned int u; } cv;
    cv.h = __float22bfloat162_rn(float2{a, b});
    return cv.u;
}
// dtype-agnostic scalar load (fp32 flag is wave-uniform)
__device__ __forceinline__ float ldf(const void* base, long i, int fp32) {
    return fp32 ? ((const float*)base)[i] : bits2f(((const unsigned short*)base)[i]);
}
// dtype-agnostic 8-element row fragment load -> bf16 bits (vectorized both paths)
__device__ __forceinline__ short8 loadRow8(const void* base, long off, int fp32) {
    if (!fp32) {
        return *(const short8*)((const unsigned short*)base + off);
    }
    const float* f = (const float*)base + off;
    floatx4 f0 = *(const floatx4*)f;
    floatx4 f1 = *(const floatx4*)(f + 4);
    union { short8 s; uintx4 w; } o;
    o.w[0] = pk2bb(f0[0], f0[1]);
    o.w[1] = pk2bb(f0[2], f0[3]);
    o.w[2] = pk2bb(f1[0], f1[1]);
    o.w[3] = pk2bb(f1[2], f1[3]);
    return o.s;
}
__device__ __forceinline__ float lclamp(float z) {  // NaN-laundering clamp
    return fminf(fmaxf(z, -1e4f), 1e4f);
}

// ---------------------------------------------------------------------------
// Probe: decide if float tensors are fp32 or bf16.
// ---------------------------------------------------------------------------
__global__ void k_probe(const unsigned short* __restrict__ Wb, int* __restrict__ flag) {
    int t = threadIdx.x;                 // 64 threads
    unsigned short u = Wb[t * 2];        // even-indexed u16
    unsigned e = (u >> 7) & 0xFF;        // bf16 exponent field
    int in = (e >= 0x60 && e <= 0x8F) ? 1 : 0;
    unsigned long long m = __ballot(in);
    if (t == 0) flag[0] = (__popcll(m) < 32) ? 1 : 0;   // 1 => fp32
}

// ---------------------------------------------------------------------------
// K1: per-atom projection into GATHER-FRIENDLY layout:
//   P_u16[a*256 + half*128 + n0*8 + tt]  holds column (tt*16+n0) of half
// ---------------------------------------------------------------------------
__global__ __launch_bounds__(256) void k_atom_proj(
    const void* __restrict__ atom,
    const void* __restrict__ Wv,         // [192][128]
    const void* __restrict__ bv,         // [128]
    __hip_bfloat16* __restrict__ P, int N, const int* __restrict__ flagp)
{
    const int fp32 = *flagp;
    const int t = threadIdx.x;
    const int wave = t >> 6, lane = t & 63;
    const int half = wave & 1;
    const int pairInBlk = wave >> 1;
    const int n0 = lane & 15, kq = lane >> 4;
    unsigned short* Pu = (unsigned short*)P;

    short8 bf[8][2];
    #pragma unroll
    for (int tt = 0; tt < 8; ++tt)
        #pragma unroll
        for (int h = 0; h < 2; ++h)
            #pragma unroll
            for (int jj = 0; jj < 8; ++jj) {
                int k = half*64 + h*32 + kq*8 + jj;
                bf[tt][h][jj] = (short)f2bb(ldf(Wv, (long)k*128 + tt*16 + n0, fp32));
            }
    float bias[8];
    #pragma unroll
    for (int tt = 0; tt < 8; ++tt)
        bias[tt] = half ? 0.f : ldf(bv, tt*16 + n0, fp32);

    const long nGroups = ((long)N + 15) / 16;
    for (long g = (long)blockIdx.x*2 + pairInBlk; g < nGroups; g += (long)gridDim.x*2) {
        long a0 = g * 16;
        long am = a0 + n0;
        short8 a_lo = {}, a_hi = {};
        if (am < N) {
            a_lo = loadRow8(atom, am*64 + kq*8, fp32);
            a_hi = loadRow8(atom, am*64 + 32 + kq*8, fp32);
        }
        floatx4 acc[8];
        #pragma unroll
        for (int tt = 0; tt < 8; ++tt) {
            floatx4 c = {0.f, 0.f, 0.f, 0.f};
            c = __builtin_amdgcn_mfma_f32_16x16x32_bf16(a_lo, bf[tt][0], c, 0, 0, 0);
            c = __builtin_amdgcn_mfma_f32_16x16x32_bf16(a_hi, bf[tt][1], c, 0, 0, 0);
            acc[tt] = c;
        }
        #pragma unroll
        for (int r = 0; r < 4; ++r) {
            long a = a0 + kq*4 + r;
            if (a < N) {
                short8 v;
                #pragma unroll
                for (int tt = 0; tt < 8; ++tt)
                    v[tt] = (short)f2bb(lclamp(acc[tt][r] + bias[tt]));
                *(short8*)(Pu + a*256 + half*128 + n0*8) = v;   // 16B coalesced
            }
        }
    }
}

// ---------------------------------------------------------------------------
// K2/K4: edge pass. z_e[n] = (nbr_e @ W3)[n] + P1[src_e][n] + P2[dst_e][n]
// W3 in LDS; P gathers as uint4 words; packed f32 epilogue (v_pk_*).
// ---------------------------------------------------------------------------
template<int PHASE>
__global__ __launch_bounds__(256, 4) void k_edge(
    const void* __restrict__ nbr,
    const int* __restrict__ esrc,
    const int* __restrict__ edst,
    const void* __restrict__ Wv,
    const unsigned short* __restrict__ Pb,   // bf16 bits, [N][2][16][8]
    const float* __restrict__ coef,
    float* __restrict__ outAcc,
    long E, const int* __restrict__ flagp)
{
    __shared__ unsigned short s_w[8192];     // 16 frags x 64 lanes x 8 u16 = 16KB
    __shared__ float s_sum[128], s_ss[128];
    const int fp32 = *flagp;
    const int t = threadIdx.x;
    const int wave = t >> 6, lane = t & 63;
    const int n0 = lane & 15, kq = lane >> 4;

    // stage W3 fragments: frag f = tt*2+h; s_w[f*512 + l*8 + jj]
    for (int idx = t; idx < 8192; idx += 256) {
        int f  = idx >> 9;
        int l  = (idx >> 3) & 63;
        int jj = idx & 7;
        int tt = f >> 1, h = f & 1;
        int k = 128 + h*32 + (l >> 4)*8 + jj;
        s_w[idx] = f2bb(ldf(Wv, (long)k*128 + tt*16 + (l & 15), fp32));
    }
    if (PHASE == 0 && t < 128) { s_sum[t] = 0.f; s_ss[t] = 0.f; }
    __syncthreads();

    float sc[8], sh[8];
    if (PHASE == 1) {
        #pragma unroll
        for (int tt = 0; tt < 8; ++tt) {
            sc[tt] = coef[tt*16 + n0];
            sh[tt] = coef[128 + tt*16 + n0];
        }
    }
    f32x2 lsum2[4], lss2[4];
    if (PHASE == 0) {
        #pragma unroll
        for (int j = 0; j < 4; ++j) { lsum2[j] = f32x2{0.f, 0.f}; lss2[j] = f32x2{0.f, 0.f}; }
    }

    const unsigned short* swl = &s_w[lane * 8];   // per-lane fragment base

    const long nGroups = (E + 15) / 16;
    for (long g = (long)blockIdx.x*4 + wave; g < nGroups; g += (long)gridDim.x*4) {
        const long e0 = g * 16;
        const bool full = (e0 + 16 <= E);

        // endpoint indices: 4 consecutive edges per quarter-wave, one 16B load
        intx4 sv, dv;
        if (full) {
            sv = *(const intx4*)(esrc + e0 + kq*4);
            dv = *(const intx4*)(edst + e0 + kq*4);
        } else {
            #pragma unroll
            for (int r = 0; r < 4; ++r) {
                long er = e0 + kq*4 + r;
                sv[r] = (er < E) ? esrc[er] : 0;
                dv[r] = (er < E) ? edst[er] : 0;
            }
        }
        // P gathers: 8 independent 16B loads as packed-bf16 words.
        uintx4 vs[4], vd[4];
        #pragma unroll
        for (int r = 0; r < 4; ++r) {
            vs[r] = *(const uintx4*)(Pb + (long)sv[r]*256 + n0*8);
            vd[r] = *(const uintx4*)(Pb + (long)dv[r]*256 + 128 + n0*8);
        }
        // A rows (nbr stream)
        long ea = e0 + n0;
        short8 a_lo = {}, a_hi = {};
        if (ea < E) {
            a_lo = loadRow8(nbr, ea*64 + kq*8, fp32);
            a_hi = loadRow8(nbr, ea*64 + 32 + kq*8, fp32);
        }
        // u = nbr @ W3 (B fragments from LDS; overlaps with gathers in flight)
        floatx4 acc[8];
        #pragma unroll
        for (int tt = 0; tt < 8; ++tt) {
            short8 b0 = *(const short8*)(swl + (tt*2 + 0)*512);
            short8 b1 = *(const short8*)(swl + (tt*2 + 1)*512);
            floatx4 c = {0.f, 0.f, 0.f, 0.f};
            c = __builtin_amdgcn_mfma_f32_16x16x32_bf16(a_lo, b0, c, 0, 0, 0);
            c = __builtin_amdgcn_mfma_f32_16x16x32_bf16(a_hi, b1, c, 0, 0, 0);
            acc[tt] = c;
        }

        if (PHASE == 0) {
            if (full) {
                #pragma unroll
                for (int r = 0; r < 4; ++r)
                    #pragma unroll
                    for (int j = 0; j < 4; ++j) {        // word j = features (2j,2j+1)*16+n0
                        f32x2 ps = unpk(vs[r][j]);
                        f32x2 pd = unpk(vd[r][j]);
                        f32x2 a; a[0] = acc[2*j][r]; a[1] = acc[2*j+1][r];
                        f32x2 z = a + ps + pd;           // v_pk_add_f32 x2
                        lsum2[j] += z;                   // v_pk_add_f32
                        lss2[j]  += z * z;               // v_pk_fma_f32
                    }
            } else {
                #pragma unroll
                for (int r = 0; r < 4; ++r) {
                    long er = e0 + kq*4 + r;
                    if (er < E)
                        #pragma unroll
                        for (int j = 0; j < 4; ++j) {
                            f32x2 ps = unpk(vs[r][j]);
                            f32x2 pd = unpk(vd[r][j]);
                            f32x2 a; a[0] = acc[2*j][r]; a[1] = acc[2*j+1][r];
                            f32x2 z = a + ps + pd;
                            lsum2[j] += z;
                            lss2[j]  += z * z;
                        }
                }
            }
        } else {
            #pragma unroll
            for (int r = 0; r < 4; ++r) {
                long er = e0 + kq*4 + r;
                if (!full && er >= E) continue;
                f32x2 zh[4];
                #pragma unroll
                for (int j = 0; j < 4; ++j) {
                    f32x2 ps = unpk(vs[r][j]);
                    f32x2 pd = unpk(vd[r][j]);
                    f32x2 a;  a[0] = acc[2*j][r];  a[1] = acc[2*j+1][r];
                    f32x2 s2; s2[0] = sc[2*j];     s2[1] = sc[2*j+1];
                    f32x2 h2; h2[0] = sh[2*j];     h2[1] = sh[2*j+1];
                    zh[j] = (a + ps + pd) * s2 + h2;     // pk_add x2 + pk_fma
                }
                float* ob = outAcc + (long)dv[r]*64 + n0;
                #pragma unroll
                for (int q = 0; q < 4; ++q) {            // filter tt=q, core tt=q+4
                    float f = zh[q >> 1][q & 1];
                    float c = zh[2 + (q >> 1)][q & 1];
                    float sig = __builtin_amdgcn_rcpf(1.f + __expf(-f));
                    float sp  = fmaxf(c, 0.f) + __logf(1.f + __expf(-fabsf(c)));
                    atomicAdd(ob + q*16, sig * sp);
                }
            }
        }
    }
    if (PHASE == 0) {
        __syncthreads();
        #pragma unroll
        for (int j = 0; j < 4; ++j) {
            atomicAdd(&s_sum[(2*j)*16 + n0],   lsum2[j][0]);
            atomicAdd(&s_sum[(2*j+1)*16 + n0], lsum2[j][1]);
            atomicAdd(&s_ss[(2*j)*16 + n0],    lss2[j][0]);
            atomicAdd(&s_ss[(2*j+1)*16 + n0],  lss2[j][1]);
        }
        __syncthreads();
        if (t < 128) {
            atomicAdd(&outAcc[t], s_sum[t]);
            atomicAdd(&outAcc[128 + t], s_ss[t]);
        }
    }
}

// ---------------------------------------------------------------------------
__global__ void k_fin1(const float* __restrict__ stats,
                       const void* __restrict__ gamma,
                       const void* __restrict__ beta,
                       float* __restrict__ coef, float invE,
                       const int* __restrict__ flagp)
{
    const int fp32 = *flagp;
    int t = threadIdx.x;  // 128
    float mean = stats[t] * invE;
    float var  = fmaxf(stats[128 + t] * invE - mean * mean, 0.f);
    float sc = ldf(gamma, t, fp32) * rsqrtf(var + 1e-5f);
    coef[t] = sc;
    coef[128 + t] = ldf(beta, t, fp32) - mean * sc;
}

__global__ void k_au_stats(const float* __restrict__ au, float* __restrict__ stats, int N)
{
    __shared__ float s_red[256];
    int t = threadIdx.x;
    int j = t & 63, r = t >> 6;
    float lsum = 0.f, lss = 0.f;
    for (int base = blockIdx.x * 4; base < N; base += gridDim.x * 4) {
        int a = base + r;
        if (a < N) { float v = au[(long)a*64 + j]; lsum += v; lss += v*v; }
    }
    s_red[t] = lsum; __syncthreads();
    if (t < 64) atomicAdd(&stats[j], s_red[j] + s_red[j+64] + s_red[j+128] + s_red[j+192]);
    __syncthreads();
    s_red[t] = lss; __syncthreads();
    if (t < 64) atomicAdd(&stats[64+j], s_red[j] + s_red[j+64] + s_red[j+128] + s_red[j+192]);
}

__global__ void k_fin2(const float* __restrict__ stats,
                       const void* __restrict__ gamma,
                       const void* __restrict__ beta,
                       float* __restrict__ coef, float invN,
                       const int* __restrict__ flagp)
{
    const int fp32 = *flagp;
    int t = threadIdx.x;  // 64
    float mean = stats[t] * invN;
    float var  = fmaxf(stats[64 + t] * invN - mean * mean, 0.f);
    float sc = ldf(gamma, t, fp32) * rsqrtf(var + 1e-5f);
    coef[t] = sc;
    coef[64 + t] = ldf(beta, t, fp32) - mean * sc;
}

__global__ void k_out(const void* __restrict__ atom,
                      const float* __restrict__ au,
                      const float* __restrict__ coef2,
                      void* __restrict__ out, long total,
                      const int* __restrict__ flagp)
{
    const int fp32 = *flagp;
    long i = (long)blockIdx.x * blockDim.x + threadIdx.x;
    if (i >= total) return;
    int j = (int)(i & 63);
    float x = lclamp(ldf(atom, i, fp32) + au[i] * coef2[j] + coef2[64 + j]);
    float sp = fmaxf(x, 0.f) + log1pf(__expf(-fabsf(x)));
    if (fp32) ((float*)out)[i] = sp;
    else      ((__hip_bfloat16*)out)[i] = __float2bfloat16(sp);
}

// ---------------------------------------------------------------------------
extern "C" void kernel_launch(void* const* d_in, const int* in_sizes, int n_in,
                              void* d_out, int out_size, void* d_ws, size_t ws_size,
                              hipStream_t stream)
{
    const void* atom = d_in[0];
    const void* nbr  = d_in[1];
    const int* esrc = (const int*)d_in[2];
    const int* edst = (const int*)d_in[3];
    const void* Wv  = d_in[4];
    const void* bv  = d_in[5];
    const void* g1  = d_in[6];
    const void* be1 = d_in[7];
    const void* g2  = d_in[8];
    const void* be2 = d_in[9];

    const int  N = in_sizes[0] / 64;
    const long E = (long)in_sizes[1] / 64;

    char* w = (char*)d_ws;
    __hip_bfloat16* P = (__hip_bfloat16*)w;  w += (size_t)N * 256 * sizeof(__hip_bfloat16);
    float* au     = (float*)w;               w += (size_t)N * 64 * sizeof(float);
    float* stats1 = (float*)w;               w += 256 * sizeof(float);
    float* stats2 = (float*)w;               w += 128 * sizeof(float);
    float* coef1  = (float*)w;               w += 256 * sizeof(float);
    float* coef2  = (float*)w;               w += 128 * sizeof(float);
    int* flagp    = (int*)w;

    hipMemsetAsync(au, 0, (size_t)N * 64 * sizeof(float), stream);
    hipMemsetAsync(stats1, 0, 384 * sizeof(float), stream);

    k_probe<<<1, 64, 0, stream>>>((const unsigned short*)Wv, flagp);
    k_atom_proj<<<1024, 256, 0, stream>>>(atom, Wv, bv, P, N, flagp);
    k_edge<0><<<2048, 256, 0, stream>>>(nbr, esrc, edst, Wv,
                                        (const unsigned short*)P, nullptr, stats1, E, flagp);
    k_fin1<<<1, 128, 0, stream>>>(stats1, g1, be1, coef1, 1.0f / (float)E, flagp);
    k_edge<1><<<2048, 256, 0, stream>>>(nbr, esrc, edst, Wv,
                                        (const unsigned short*)P, coef1, au, E, flagp);
    k_au_stats<<<1024, 256, 0, stream>>>(au, stats2, N);
    k_fin2<<<1, 64, 0, stream>>>(stats2, g2, be2, coef2, 1.0f / (float)N, flagp);
    long total = (long)N * 64;
    k_out<<<(int)((total + 255) / 256), 256, 0, stream>>>(atom, au, coef2,
                                                          d_out, total, flagp);
}